// Round 4
// baseline (439.213 us; speedup 1.0000x reference)
//
#include <hip/hip_runtime.h>
#include <hip/hip_bf16.h>
#include <math.h>

// Problem dims (fixed by reference): T=2, B=16, L=2048, D=512, G=1024
#define TT 2
#define BB 16
#define LL 2048
#define NN 4096   // T*L
#define DD 512
#define GG 1024
#define SCALE 0.044194173824159216f   // 1/sqrt(512)
#define LOG2E 1.4426950408889634f
#define QSCL (SCALE * LOG2E)          // folded into F-table coeffs and G
#define C_IP 0.051905126482615036f    // log2(10000)/256

typedef unsigned short ushort_t;
typedef short short8 __attribute__((ext_vector_type(8)));   // 8 bf16 = 4 VGPR (MFMA A/B frag)
typedef float f32x4 __attribute__((ext_vector_type(4)));    // MFMA C/D frag

__device__ __forceinline__ float inv_pos_f(int dhalf) {
    return exp2f(-C_IP * (float)dhalf);      // 10000^(-dhalf/256)
}
__device__ __forceinline__ unsigned short f2b(float f) {  // fp32 -> bf16 bits, RNE
    union { float f; unsigned u; } x; x.f = f;
    unsigned r = x.u + 0x7fffu + ((x.u >> 16) & 1u);
    return (unsigned short)(r >> 16);
}
__device__ __forceinline__ float b2f(unsigned short u) {
    union { unsigned u; float f; } x; x.u = ((unsigned)u) << 16;
    return x.f;
}

// ---------------- embT generator ----------------
__global__ void genT_kernel(const float* __restrict__ times,
                            const float* __restrict__ type_emb,
                            ushort_t* __restrict__ embT) {
    __shared__ float s_tm[64];
    __shared__ float s_te[DD];
    const int bid = blockIdx.x;
    const int b = bid >> 6;
    const int ntile = bid & 63;            // 64-n tile; t = ntile>>5
    const int t = ntile >> 5;
    const int l0 = (ntile & 31) * 64;
    const int tid = threadIdx.x;           // 256

    if (tid < 64) s_tm[tid] = times[(size_t)(t * BB + b) * LL + l0 + tid];
    s_te[tid]       = type_emb[t * DD + tid];
    s_te[tid + 256] = type_emb[t * DD + tid + 256];
    __syncthreads();

    const int dsub = tid >> 3;
    const int nc = (tid & 7) * 8;
#pragma unroll 4
    for (int pass = 0; pass < 16; ++pass) {
        const int d = pass * 32 + dsub;
        const float ip = inv_pos_f(d >> 1);
        const float te = s_te[d];
        const bool use_cos = (d & 1);
        union { ushort_t us[8]; short8 v; } o;
#pragma unroll
        for (int j = 0; j < 8; ++j) {
            const float tm = s_tm[nc + j];
            const float th = tm * ip;
            const float v = use_cos ? __cosf(th) : __sinf(th);
            o.us[j] = f2b((v + te) * ((tm != 0.0f) ? 1.0f : 0.0f));
        }
        *reinterpret_cast<short8*>(
            embT + ((size_t)b * DD + d) * NN + (size_t)ntile * 64 + nc) = o.v;
    }
}

// ---------------- F table, cubic Hermite coeffs per unit interval ----------------
// F(delta) = sum_j cos(delta * w_j), w_j = 10000^(-j/256).
// Interval i covers delta in [i-1024, i-1023]; coeffs (a,b,c,e) give
// F(i-1024+s) ~= a + s(b + s(c + s*e)), pre-scaled by QSCL.
__global__ void ftab4_kernel(float* __restrict__ F4) {   // 2048 float4
    const int tid = threadIdx.x;                 // 256
    const int e = blockIdx.x * 32 + (tid >> 3);  // 8 threads per entry
    const int jj = tid & 7;
    const float d0 = (float)e - 1024.0f;
    const float d1 = d0 + 1.0f;
    float F0 = 0.f, F1 = 0.f, D0 = 0.f, D1 = 0.f;
    for (int j = jj; j < 256; j += 8) {
        const float w = inv_pos_f(j);
        float s0, c0, s1, c1;
        __sincosf(d0 * w, &s0, &c0);
        __sincosf(d1 * w, &s1, &c1);
        F0 += c0; D0 -= w * s0;
        F1 += c1; D1 -= w * s1;
    }
#pragma unroll
    for (int off = 1; off < 8; off <<= 1) {
        F0 += __shfl_xor(F0, off, 64); F1 += __shfl_xor(F1, off, 64);
        D0 += __shfl_xor(D0, off, 64); D1 += __shfl_xor(D1, off, 64);
    }
    if (jj == 0) {
        const float cc = 3.f * (F1 - F0) - 2.f * D0 - D1;
        const float ee = 2.f * (F0 - F1) + D0 + D1;
        float4 v;
        v.x = F0 * QSCL; v.y = D0 * QSCL; v.z = cc * QSCL; v.w = ee * QSCL;
        reinterpret_cast<float4*>(F4)[e] = v;
    }
}

// ---------------- G table: G[t][g] = type_emb[t] . sinusoid(mid_g) ----------------
__global__ void gq_kernel(const float* __restrict__ type_emb, float* __restrict__ G) {
    const int g = blockIdx.x;
    const int tid = threadIdx.x;   // 256
    const float mid = (float)g + 0.5f;
    float a0 = 0.f, a1 = 0.f;
#pragma unroll
    for (int i = 0; i < 2; ++i) {
        const int d = i * 256 + tid;
        const float th = mid * inv_pos_f(d >> 1);
        const float v = (d & 1) ? cosf(th) : sinf(th);
        a0 += v * type_emb[d];
        a1 += v * type_emb[DD + d];
    }
#pragma unroll
    for (int off = 32; off; off >>= 1) {
        a0 += __shfl_xor(a0, off, 64);
        a1 += __shfl_xor(a1, off, 64);
    }
    __shared__ float r0[4], r1[4];
    const int wv = tid >> 6;
    if ((tid & 63) == 0) { r0[wv] = a0; r1[wv] = a1; }
    __syncthreads();
    if (tid == 0) {
        G[g]      = r0[0] + r0[1] + r0[2] + r0[3];
        G[GG + g] = r1[0] + r1[1] + r1[2] + r1[3];
    }
}

// ---------------- flash attention v6: barrier-free independent waves ----------------
// R8 lesson: attn5's pipes were all <20% busy; ~80% of each 3750-cyc tile was
// the 4-wave lockstep barrier pair around the sP handoff. v6 removes the
// handoff: each lane computes scores for exactly the (n,g) slots of its OWN
// B-fragment (k=quad*8+j, col=l15), so P is born in registers in MFMA layout.
// Waves are fully independent (16 g x 256 d each; 2 g-groups x 2 d-halves per
// block); the ONLY sync is one __syncthreads after the sF table fill.
// Scores are computed twice (once per d-half) -- cheap VALU vs barrier stalls.
template <int NS>
__global__ __launch_bounds__(256, 2)
void attn6(const float* __restrict__ times,
           const ushort_t* __restrict__ embT,
           const float* __restrict__ Ft4,     // 2048 float4 cubic coeffs (pre-scaled)
           const float* __restrict__ Gt,      // [2][GG]
           const int* __restrict__ real_len,
           ushort_t* __restrict__ pO,         // [NS][B][G][D] bf16 partial O
           float* __restrict__ pl) {          // [NS][B][G] partial l
    __shared__ float4 sF[2048];               // 32KB cubic table (read-only after fill)

    constexpr int TPS = 128 / NS;             // tiles per split
    const int idx = blockIdx.x;               // low 3 bits = XCD slot = b%8
    const int xcd = idx & 7;
    const int gt = (idx >> 3) & 31;
    const int hi = idx >> 8;                  // [0, NS*2)
    const int b = xcd + ((hi & 1) << 3);
    const int s = hi >> 1;
    const int g0 = gt * 32;

    const int tid = threadIdx.x;              // 256
    const int lane = tid & 63;
    const int w = tid >> 6;                   // 4 waves
    const int l15 = lane & 15;
    const int quad = lane >> 4;               // 0..3
    const int dh = w & 1;                     // d-half: [0,256) or [256,512)
    const int gh = w >> 1;                    // g-subgroup (16 g each)

    const int gme = g0 + gh * 16 + l15;       // this lane's g column
    const float gmid = (float)gme + 0.5f;
    const float c0 = Gt[gme] * QSCL - 4.0f;   // per-half exp2-arg constant
    const float c1 = Gt[GG + gme] * QSCL - 4.0f;

    const ushort_t* embTB = embT + (size_t)b * DD * NN;

    const int rl0 = real_len[b];
    const int rl1 = real_len[BB + b];
    const int e0 = (rl0 + 31) >> 5;           // valid tiles in t0 half [0,64)
    const int e1 = (rl1 + 31) >> 5;           // valid tiles in t1 half [64,128)
    const int first = s * TPS;                // split never crosses tile 64
    int count;
    if (first < 64) count = min(max(e0 - first, 0), TPS);
    else            count = min(max(64 + e1 - first, 0), TPS);

    f32x4 accO[16];
#pragma unroll
    for (int i = 0; i < 16; ++i) accO[i] = (f32x4)0.f;
    float ls = 0.f;

    // A-fragments: tf[mt] = embT[d = dh*256 + mt*16 + l15][n = nt*32 + quad*8 + j]
    short8 tf[16];
    auto prefetchT = [&](int nt) {
        const ushort_t* trow = embTB + (size_t)(dh * 256 + l15) * NN + nt * 32 + quad * 8;
#pragma unroll
        for (int mt = 0; mt < 16; ++mt)
            tf[mt] = *reinterpret_cast<const short8*>(trow + (size_t)mt * 16 * NN);
    };
    struct f8 { float4 a, b; };
    auto times8 = [&](int nt) -> f8 {
        const int n = nt * 32 + quad * 8;
        const float* base = times + (size_t)((n >> 11) * BB + b) * LL + (n & (LL - 1));
        f8 r;
        r.a = *reinterpret_cast<const float4*>(base);
        r.b = *reinterpret_cast<const float4*>(base + 4);
        return r;
    };

    float4 hv[8];     // cubic coeffs per score point (prefetched for current tile)
    float sr[8];      // fractional offset per score point
    auto gather = [&](f8 t8) {
        const float tt[8] = {t8.a.x, t8.a.y, t8.a.z, t8.a.w,
                             t8.b.x, t8.b.y, t8.b.z, t8.b.w};
#pragma unroll
        for (int r = 0; r < 8; ++r) {
            const float u = (tt[r] - gmid) + 1024.0f;   // in (0.5, 2047.5)
            const int i = (int)u;
            sr[r] = u - (float)i;
            hv[r] = sF[i];
        }
    };

    f8 t8n;
    if (count > 0) {
        // fill LDS table (coalesced; L2-resident source)
        const float4* Fg = reinterpret_cast<const float4*>(Ft4);
#pragma unroll
        for (int i = 0; i < 8; ++i) sF[tid + i * 256] = Fg[tid + i * 256];
        prefetchT(first);
        const f8 t80 = times8(first);
        __syncthreads();                       // table visible; ONLY sync in kernel
        gather(t80);
        if (count > 1) t8n = times8(first + 1);
    }

    for (int k = 0; k < count; ++k) {
        const int cur = first + k;

        // ---- scores for tile cur: lane owns n = cur*32 + quad*8 + j, g = gme
        const int nb = cur * 32;
        const int rl = (nb >= LL) ? rl1 : rl0;
        const float cc = (nb >= LL) ? c1 : c0;
        const int lb = (nb & (LL - 1)) + quad * 8;
        float p[8];
#pragma unroll
        for (int r = 0; r < 8; ++r) {
            const float sv = sr[r];
            const float4 h = hv[r];
            const float Fv = h.x + sv * (h.y + sv * (h.z + sv * h.w));
            p[r] = (lb + r < rl) ? exp2f(Fv + cc) : 0.0f;
        }
        ls += ((p[0] + p[1]) + (p[2] + p[3])) + ((p[4] + p[5]) + (p[6] + p[7]));

        // P is already in B-fragment layout: element j at k=quad*8+j, col=l15
        union { unsigned short us[8]; short8 v; } pk;
#pragma unroll
        for (int r = 0; r < 8; ++r) pk.us[r] = f2b(p[r]);
        const short8 bP = pk.v;

        // ---- prefetch next tile's gathers (LDS) + times (global); MFMA hides them
        if (k + 1 < count) {
            gather(t8n);
            if (k + 2 < count) t8n = times8(cur + 2);
        }

        // ---- GEMM2: 16 independent MFMAs, A = tf regs (prefetched last iter)
        __builtin_amdgcn_s_setprio(1);
#pragma unroll
        for (int mt = 0; mt < 16; ++mt)
            accO[mt] = __builtin_amdgcn_mfma_f32_16x16x32_bf16(tf[mt], bP, accO[mt], 0, 0, 0);
        __builtin_amdgcn_s_setprio(0);

        if (k + 1 < count) prefetchT(cur + 1);   // refill tf after MFMA consumed it
    }

    // ---- l reduction: sum over quads (all n-slots of each g live in 4 lanes)
    ls += __shfl_xor(ls, 16, 64);
    ls += __shfl_xor(ls, 32, 64);
    if (dh == 0 && lane < 16)
        pl[((size_t)s * BB + b) * GG + gme] = ls;   // lane<16 => l15==lane, quad==0

    ushort_t* po = pO + (((size_t)s * BB + b) * GG) * DD;
#pragma unroll
    for (int mt = 0; mt < 16; ++mt) {
        union { unsigned short us[4]; unsigned long long u64; } pk2;
        pk2.us[0] = f2b(accO[mt][0]); pk2.us[1] = f2b(accO[mt][1]);
        pk2.us[2] = f2b(accO[mt][2]); pk2.us[3] = f2b(accO[mt][3]);
        const int d = dh * 256 + mt * 16 + quad * 4;
        *reinterpret_cast<unsigned long long*>(po + (size_t)gme * DD + d) = pk2.u64;
    }
}

// ---------------- combine: out = (sum_s O_s) / (sum_s l_s) ----------------
template <int NS>
__global__ void combine3(const ushort_t* __restrict__ pO,
                         const float* __restrict__ pl,
                         float* __restrict__ out) {
    const size_t i4 = (size_t)blockIdx.x * 256 + threadIdx.x;
    const size_t base = i4 * 4;                 // 4 d's
    const size_t bg = base >> 9;                // (b*G+g), DD=512
    float lsum = 0.f;
#pragma unroll
    for (int s = 0; s < NS; ++s) lsum += pl[(size_t)s * BB * GG + bg];
    const float inv = 1.0f / lsum;
    float o[4] = {0.f, 0.f, 0.f, 0.f};
#pragma unroll
    for (int s = 0; s < NS; ++s) {
        union { unsigned long long u64; unsigned short us[4]; } pk;
        pk.u64 = *reinterpret_cast<const unsigned long long*>(
            pO + (size_t)s * BB * GG * DD + base);
#pragma unroll
        for (int j = 0; j < 4; ++j) o[j] += b2f(pk.us[j]);
    }
    float4 v;
    v.x = o[0] * inv; v.y = o[1] * inv; v.z = o[2] * inv; v.w = o[3] * inv;
    *reinterpret_cast<float4*>(out + base) = v;
}

// ---------------- round-2 proven fallback (tiny ws) ----------------
__global__ void emb_kernel(const float* __restrict__ times,
                           const float* __restrict__ type_emb,
                           ushort_t* __restrict__ emb) {
    const int row = blockIdx.x;
    const int b = row >> 12;
    const int n = row & (NN - 1);
    const int t = n >> 11;
    const int l = n & (LL - 1);
    const float tm = times[(size_t)(t * BB + b) * LL + l];
    const float pad = (tm != 0.0f) ? 1.0f : 0.0f;
    const int tid = threadIdx.x;
#pragma unroll
    for (int i = 0; i < 2; ++i) {
        int d = i * 256 + tid;
        float theta = tm * inv_pos_f(d >> 1);
        float v = (d & 1) ? cosf(theta) : sinf(theta);
        v = (v + type_emb[t * DD + d]) * pad;
        emb[(size_t)row * DD + d] = f2b(v);
    }
}
__global__ void qgrid_kernel(float* __restrict__ qbuf) {
    const int g = blockIdx.x;
    const int tid = threadIdx.x;
    const float mid = (float)g + 0.5f;
#pragma unroll
    for (int i = 0; i < 4; ++i) {
        int d = i * 128 + tid;
        float theta = mid * inv_pos_f(d >> 1);
        float v = (d & 1) ? cosf(theta) : sinf(theta);
        qbuf[(size_t)g * DD + d] = v;
    }
}
__global__ void attn_kernel(const ushort_t* __restrict__ emb,
                            const float* __restrict__ qbuf,
                            const int* __restrict__ real_len,
                            float* __restrict__ out) {
    __shared__ float s_lds[NN];
    __shared__ float q_s[DD];
    __shared__ float red[8];
    const int blk = blockIdx.x;
    const int b = blk >> 10;
    const int g = blk & (GG - 1);
    const int tid = threadIdx.x;
    const int lane = tid & 63;
    const int wave = tid >> 6;
    q_s[tid]       = qbuf[(size_t)g * DD + tid];
    q_s[tid + 256] = qbuf[(size_t)g * DD + tid + 256];
    __syncthreads();
    float qr[8];
#pragma unroll
    for (int j = 0; j < 8; ++j) qr[j] = q_s[lane * 8 + j];
    const unsigned int* embB =
        reinterpret_cast<const unsigned int*>(emb) + (size_t)b * NN * (DD / 2);
#pragma unroll 2
    for (int it = 0; it < NN / 4; ++it) {
        const int n = it * 4 + wave;
        const uint4 raw = *reinterpret_cast<const uint4*>(embB + (size_t)n * (DD / 2) + lane * 4);
        float sacc = 0.f;
        sacc = fmaf(__uint_as_float(raw.x << 16),         qr[0], sacc);
        sacc = fmaf(__uint_as_float(raw.x & 0xffff0000u), qr[1], sacc);
        sacc = fmaf(__uint_as_float(raw.y << 16),         qr[2], sacc);
        sacc = fmaf(__uint_as_float(raw.y & 0xffff0000u), qr[3], sacc);
        sacc = fmaf(__uint_as_float(raw.z << 16),         qr[4], sacc);
        sacc = fmaf(__uint_as_float(raw.z & 0xffff0000u), qr[5], sacc);
        sacc = fmaf(__uint_as_float(raw.w << 16),         qr[6], sacc);
        sacc = fmaf(__uint_as_float(raw.w & 0xffff0000u), qr[7], sacc);
#pragma unroll
        for (int off = 32; off; off >>= 1) sacc += __shfl_xor(sacc, off, 64);
        if (lane == 0) s_lds[n] = sacc * SCALE;
    }
    __syncthreads();
    const int rl0 = real_len[b];
    const int rl1 = real_len[BB + b];
    float m = -INFINITY;
    float sv[16];
#pragma unroll
    for (int i = 0; i < 16; ++i) {
        const int n = i * 256 + tid;
        float sc = s_lds[n];
        const int l = n & (LL - 1);
        const bool valid = l < ((n < LL) ? rl0 : rl1);
        sc = valid ? sc : -INFINITY;
        sv[i] = sc;
        m = fmaxf(m, sc);
    }
#pragma unroll
    for (int off = 32; off; off >>= 1) m = fmaxf(m, __shfl_xor(m, off, 64));
    if (lane == 0) red[wave] = m;
    __syncthreads();
    m = fmaxf(fmaxf(red[0], red[1]), fmaxf(red[2], red[3]));
    float lsum = 0.f;
#pragma unroll
    for (int i = 0; i < 16; ++i) {
        const int n = i * 256 + tid;
        const float e = expf(sv[i] - m);
        s_lds[n] = e;
        lsum += e;
    }
#pragma unroll
    for (int off = 32; off; off >>= 1) lsum += __shfl_xor(lsum, off, 64);
    if (lane == 0) red[4 + wave] = lsum;
    __syncthreads();
    const float inv_l = 1.0f / (red[4] + red[5] + red[6] + red[7]);
    float acc[8] = {0.f, 0.f, 0.f, 0.f, 0.f, 0.f, 0.f, 0.f};
#pragma unroll 2
    for (int kk = 0; kk < NN / 4; ++kk) {
        const int n = kk * 4 + wave;
        const float p = s_lds[n];
        const uint4 raw = *reinterpret_cast<const uint4*>(embB + (size_t)n * (DD / 2) + lane * 4);
        acc[0] = fmaf(p, __uint_as_float(raw.x << 16),         acc[0]);
        acc[1] = fmaf(p, __uint_as_float(raw.x & 0xffff0000u), acc[1]);
        acc[2] = fmaf(p, __uint_as_float(raw.y << 16),         acc[2]);
        acc[3] = fmaf(p, __uint_as_float(raw.y & 0xffff0000u), acc[3]);
        acc[4] = fmaf(p, __uint_as_float(raw.z << 16),         acc[4]);
        acc[5] = fmaf(p, __uint_as_float(raw.z & 0xffff0000u), acc[5]);
        acc[6] = fmaf(p, __uint_as_float(raw.w << 16),         acc[6]);
        acc[7] = fmaf(p, __uint_as_float(raw.w & 0xffff0000u), acc[7]);
    }
    __syncthreads();
    *reinterpret_cast<float4*>(&s_lds[wave * DD + lane * 8])     = make_float4(acc[0], acc[1], acc[2], acc[3]);
    *reinterpret_cast<float4*>(&s_lds[wave * DD + lane * 8 + 4]) = make_float4(acc[4], acc[5], acc[6], acc[7]);
    __syncthreads();
    {
        const int d0 = tid * 2;
        const float o0 = (s_lds[d0]     + s_lds[DD + d0]     + s_lds[2 * DD + d0]     + s_lds[3 * DD + d0])     * inv_l;
        const float o1 = (s_lds[d0 + 1] + s_lds[DD + d0 + 1] + s_lds[2 * DD + d0 + 1] + s_lds[3 * DD + d0 + 1]) * inv_l;
        *reinterpret_cast<float2*>(out + (size_t)blk * DD + d0) = make_float2(o0, o1);
    }
}

extern "C" void kernel_launch(void* const* d_in, const int* in_sizes, int n_in,
                              void* d_out, int out_size, void* d_ws, size_t ws_size,
                              hipStream_t stream) {
    const float* times    = (const float*)d_in[0];
    const float* type_emb = (const float*)d_in[1];
    const int*   real_len = (const int*)d_in[2];
    float* out = (float*)d_out;

    const size_t embTBytes = (size_t)BB * DD * NN * sizeof(ushort_t);    // 64 MiB
    const size_t tabBytes  = 64 * 1024;                                  // F4 (32KB) + G (8KB) + pad
    const size_t pOslice   = (size_t)BB * GG * DD * sizeof(ushort_t);    // 16 MiB (bf16)
    const size_t plslice   = (size_t)BB * GG * sizeof(float);            // 64 KiB

    ushort_t* embT = (ushort_t*)d_ws;
    float* Ftab = (float*)((char*)d_ws + embTBytes);
    float* Gtab = (float*)((char*)d_ws + embTBytes + 32 * 1024);
    char* pbase = (char*)d_ws + embTBytes + tabBytes;

    auto need = [&](size_t ns) { return embTBytes + tabBytes + ns * (pOslice + plslice); };

    int NS = 0;
    if      (ws_size >= need(4)) NS = 4;
    else if (ws_size >= need(2)) NS = 2;

    if (NS > 0) {
        genT_kernel<<<BB * 64, 256, 0, stream>>>(times, type_emb, embT);
        ftab4_kernel<<<64, 256, 0, stream>>>(Ftab);
        gq_kernel<<<GG, 256, 0, stream>>>(type_emb, Gtab);
        ushort_t* pO = (ushort_t*)pbase;
        float* pl = (float*)(pbase + (size_t)NS * pOslice);
        if (NS == 4) {
            attn6<4><<<4 * 512, 256, 0, stream>>>(times, embT, Ftab, Gtab, real_len, pO, pl);
            combine3<4><<<(BB * GG * DD) / (256 * 4), 256, 0, stream>>>(pO, pl, out);
        } else {
            attn6<2><<<2 * 512, 256, 0, stream>>>(times, embT, Ftab, Gtab, real_len, pO, pl);
            combine3<2><<<(BB * GG * DD) / (256 * 4), 256, 0, stream>>>(pO, pl, out);
        }
    } else {
        // fallback: 66 MiB footprint (proven in round 2)
        ushort_t* emb = (ushort_t*)d_ws;
        float* qbuf = (float*)((char*)d_ws + embTBytes);
        emb_kernel<<<BB * NN, 256, 0, stream>>>(times, type_emb, emb);
        qgrid_kernel<<<GG, 128, 0, stream>>>(qbuf);
        attn_kernel<<<BB * GG, 256, 0, stream>>>(emb, qbuf, real_len, out);
    }
}

// Round 5
// 244.446 us; speedup vs baseline: 1.7968x; 1.7968x over previous
//
#include <hip/hip_runtime.h>
#include <hip/hip_bf16.h>
#include <math.h>

// Problem dims (fixed by reference): T=2, B=16, L=2048, D=512, G=1024
#define TT 2
#define BB 16
#define LL 2048
#define NN 4096   // T*L
#define DD 512
#define GG 1024
#define SCALE 0.044194173824159216f   // 1/sqrt(512)
#define LOG2E 1.4426950408889634f
#define QSCL (SCALE * LOG2E)          // folded into F-table coeffs and G
#define C_IP 0.051905126482615036f    // log2(10000)/256

typedef unsigned short ushort_t;
typedef short short8 __attribute__((ext_vector_type(8)));   // 8 bf16 = 4 VGPR (MFMA A/B frag)
typedef float f32x4 __attribute__((ext_vector_type(4)));    // MFMA C/D frag

__device__ __forceinline__ float inv_pos_f(int dhalf) {
    return exp2f(-C_IP * (float)dhalf);      // 10000^(-dhalf/256)
}
__device__ __forceinline__ unsigned short f2b(float f) {  // fp32 -> bf16 bits, RNE
    union { float f; unsigned u; } x; x.f = f;
    unsigned r = x.u + 0x7fffu + ((x.u >> 16) & 1u);
    return (unsigned short)(r >> 16);
}
__device__ __forceinline__ float b2f(unsigned short u) {
    union { unsigned u; float f; } x; x.u = ((unsigned)u) << 16;
    return x.f;
}

// ---------------- embT generator ----------------
__global__ void genT_kernel(const float* __restrict__ times,
                            const float* __restrict__ type_emb,
                            ushort_t* __restrict__ embT) {
    __shared__ float s_tm[64];
    __shared__ float s_te[DD];
    const int bid = blockIdx.x;
    const int b = bid >> 6;
    const int ntile = bid & 63;            // 64-n tile; t = ntile>>5
    const int t = ntile >> 5;
    const int l0 = (ntile & 31) * 64;
    const int tid = threadIdx.x;           // 256

    if (tid < 64) s_tm[tid] = times[(size_t)(t * BB + b) * LL + l0 + tid];
    s_te[tid]       = type_emb[t * DD + tid];
    s_te[tid + 256] = type_emb[t * DD + tid + 256];
    __syncthreads();

    const int dsub = tid >> 3;
    const int nc = (tid & 7) * 8;
#pragma unroll 4
    for (int pass = 0; pass < 16; ++pass) {
        const int d = pass * 32 + dsub;
        const float ip = inv_pos_f(d >> 1);
        const float te = s_te[d];
        const bool use_cos = (d & 1);
        union { ushort_t us[8]; short8 v; } o;
#pragma unroll
        for (int j = 0; j < 8; ++j) {
            const float tm = s_tm[nc + j];
            const float th = tm * ip;
            const float v = use_cos ? __cosf(th) : __sinf(th);
            o.us[j] = f2b((v + te) * ((tm != 0.0f) ? 1.0f : 0.0f));
        }
        *reinterpret_cast<short8*>(
            embT + ((size_t)b * DD + d) * NN + (size_t)ntile * 64 + nc) = o.v;
    }
}

// ---------------- F table, cubic Hermite coeffs per unit interval ----------------
// F(delta) = sum_j cos(delta * w_j), w_j = 10000^(-j/256).
// Interval i covers delta in [i-1024, i-1023]; coeffs (a,b,c,e) give
// F(i-1024+s) ~= a + s(b + s(c + s*e)), pre-scaled by QSCL.
__global__ void ftab4_kernel(float* __restrict__ F4) {   // 2048 float4
    const int tid = threadIdx.x;                 // 256
    const int e = blockIdx.x * 32 + (tid >> 3);  // 8 threads per entry
    const int jj = tid & 7;
    const float d0 = (float)e - 1024.0f;
    const float d1 = d0 + 1.0f;
    float F0 = 0.f, F1 = 0.f, D0 = 0.f, D1 = 0.f;
    for (int j = jj; j < 256; j += 8) {
        const float w = inv_pos_f(j);
        float s0, c0, s1, c1;
        __sincosf(d0 * w, &s0, &c0);
        __sincosf(d1 * w, &s1, &c1);
        F0 += c0; D0 -= w * s0;
        F1 += c1; D1 -= w * s1;
    }
#pragma unroll
    for (int off = 1; off < 8; off <<= 1) {
        F0 += __shfl_xor(F0, off, 64); F1 += __shfl_xor(F1, off, 64);
        D0 += __shfl_xor(D0, off, 64); D1 += __shfl_xor(D1, off, 64);
    }
    if (jj == 0) {
        const float cc = 3.f * (F1 - F0) - 2.f * D0 - D1;
        const float ee = 2.f * (F0 - F1) + D0 + D1;
        float4 v;
        v.x = F0 * QSCL; v.y = D0 * QSCL; v.z = cc * QSCL; v.w = ee * QSCL;
        reinterpret_cast<float4*>(F4)[e] = v;
    }
}

// ---------------- G table: G[t][g] = type_emb[t] . sinusoid(mid_g) ----------------
__global__ void gq_kernel(const float* __restrict__ type_emb, float* __restrict__ G) {
    const int g = blockIdx.x;
    const int tid = threadIdx.x;   // 256
    const float mid = (float)g + 0.5f;
    float a0 = 0.f, a1 = 0.f;
#pragma unroll
    for (int i = 0; i < 2; ++i) {
        const int d = i * 256 + tid;
        const float th = mid * inv_pos_f(d >> 1);
        const float v = (d & 1) ? cosf(th) : sinf(th);
        a0 += v * type_emb[d];
        a1 += v * type_emb[DD + d];
    }
#pragma unroll
    for (int off = 32; off; off >>= 1) {
        a0 += __shfl_xor(a0, off, 64);
        a1 += __shfl_xor(a1, off, 64);
    }
    __shared__ float r0[4], r1[4];
    const int wv = tid >> 6;
    if ((tid & 63) == 0) { r0[wv] = a0; r1[wv] = a1; }
    __syncthreads();
    if (tid == 0) {
        G[g]      = r0[0] + r0[1] + r0[2] + r0[3];
        G[GG + g] = r1[0] + r1[1] + r1[2] + r1[3];
    }
}

// ---------------- flash attention v7: attn5 skeleton, G_block 32 -> 64 ----------------
// R9 lesson (attn6 -76%): embT register-stream through L2/L3 is the binding
// resource (~1.07GB at G_block=32 ~= the whole 203us). Traffic scales as
// G/G_block, so double the per-block g range: each block now produces
// 64 g x 512 d. Waves keep EXCLUSIVE 128-d slices (no duplication -- the
// attn6 mistake), accumulate accO[8][4] (128d x 64g), scores 8/lane, sP 64x32.
// Everything else is attn5's verified structure: cubic LDS table, sP dbuf,
// ONE barrier per tile, tf prefetched a tile ahead.
template <int NS>
__global__ __launch_bounds__(256, 2)
void attn7(const float* __restrict__ times,
           const ushort_t* __restrict__ embT,
           const float* __restrict__ Ft4,     // 2048 float4 cubic coeffs (pre-scaled)
           const float* __restrict__ Gt,      // [2][GG]
           const int* __restrict__ real_len,
           ushort_t* __restrict__ pO,         // [NS][B][G][D] bf16 partial O
           float* __restrict__ pl) {          // [NS][B][G] partial l
    __shared__ float4 sF[2048];                         // 32KB cubic table
    __shared__ __align__(16) ushort_t sP[2][64 * 40];   // P [g][n] dbuf, row stride 80B
    __shared__ float s_lred[2][64];

    constexpr int TPS = 128 / NS;             // tiles per split
    const int idx = blockIdx.x;               // low 3 bits = XCD slot = b%8
    const int xcd = idx & 7;
    const int gt = (idx >> 3) & 15;           // 16 g-blocks of 64
    const int hi = idx >> 7;                  // [0, NS*2)
    const int b = xcd + ((hi & 1) << 3);
    const int s = hi >> 1;
    const int g0 = gt * 64;

    const int tid = threadIdx.x;              // 256
    const int lane = tid & 63;
    const int w = tid >> 6;                   // 4 waves
    const int l15 = lane & 15;
    const int quad = lane >> 4;               // 0..3
    const int mt1 = w >> 1;                   // n-subtile (0/1) for this wave's scores
    const int gt1 = w & 1;                    // g-half (0/1) of the 64-g block

    // this lane's two g columns (score rows): ga and ga+16
    const int ga = g0 + gt1 * 32 + l15;
    const float gmid = (float)ga + 0.5f;
    const float ca0 = Gt[ga] * QSCL - 4.0f;
    const float ca1 = Gt[GG + ga] * QSCL - 4.0f;
    const float cb0 = Gt[ga + 16] * QSCL - 4.0f;
    const float cb1 = Gt[GG + ga + 16] * QSCL - 4.0f;

    const ushort_t* embTB = embT + (size_t)b * DD * NN;

    const int rl0 = real_len[b];
    const int rl1 = real_len[BB + b];
    const int e0 = (rl0 + 31) >> 5;           // valid tiles in t0 half [0,64)
    const int e1 = (rl1 + 31) >> 5;           // valid tiles in t1 half [64,128)
    const int first = s * TPS;                // split never crosses tile 64
    int count;
    if (first < 64) count = min(max(e0 - first, 0), TPS);
    else            count = min(max(64 + e1 - first, 0), TPS);

    f32x4 accO[8][4];
#pragma unroll
    for (int i = 0; i < 8; ++i)
#pragma unroll
        for (int j = 0; j < 4; ++j) accO[i][j] = (f32x4)0.f;
    float lsa = 0.f, lsb = 0.f;

    short8 tf[8];
    auto prefetchT = [&](int nt) {
        const ushort_t* trow = embTB + (size_t)(w * 128 + l15) * NN + nt * 32 + quad * 8;
#pragma unroll
        for (int mt = 0; mt < 8; ++mt)
            tf[mt] = *reinterpret_cast<const short8*>(trow + (size_t)mt * 16 * NN);
    };
    auto times4 = [&](int nt) -> float4 {
        const int n = nt * 32 + mt1 * 16 + quad * 4;
        return *reinterpret_cast<const float4*>(
            times + (size_t)((n >> 11) * BB + b) * LL + (n & (LL - 1)));
    };

    float4 hv[8];     // cubic coeffs: 4 n's x 2 g's
    float sr[8];
    auto gather = [&](float4 t4) {
        const float tt[4] = {t4.x, t4.y, t4.z, t4.w};
#pragma unroll
        for (int r = 0; r < 4; ++r) {
#pragma unroll
            for (int gs = 0; gs < 2; ++gs) {
                const float u = (tt[r] - (gmid + 16.0f * (float)gs)) + 1024.0f;
                const int i = (int)u;
                sr[r * 2 + gs] = u - (float)i;
                hv[r * 2 + gs] = sF[i];
            }
        }
    };

    if (count > 0) {
        // fill LDS table (coalesced; L2-resident source)
        const float4* Fg = reinterpret_cast<const float4*>(Ft4);
#pragma unroll
        for (int i = 0; i < 8; ++i) sF[tid + i * 256] = Fg[tid + i * 256];
        prefetchT(first);
        const float4 t40 = times4(first);
        __syncthreads();                       // table visible to all waves
        gather(t40);
    }
    float4 t4n;
    if (count > 1) t4n = times4(first + 1);

    for (int k = 0; k < count; ++k) {
        const int cur = first + k;
        const int buf = k & 1;

        // ---- scores for tile cur (hv/sr gathered >=1 phase ago)
        const int nb = cur * 32 + mt1 * 16 + quad * 4;
        const int rl = (nb >= LL) ? rl1 : rl0;
        const float cA = (nb >= LL) ? ca1 : ca0;
        const float cB = (nb >= LL) ? cb1 : cb0;
        const int lb = nb & (LL - 1);
        float p[8];
#pragma unroll
        for (int r = 0; r < 4; ++r) {
#pragma unroll
            for (int gs = 0; gs < 2; ++gs) {
                const float sv = sr[r * 2 + gs];
                const float4 h = hv[r * 2 + gs];
                const float Fv = h.x + sv * (h.y + sv * (h.z + sv * h.w));
                p[r * 2 + gs] = (lb + r < rl) ? exp2f(Fv + (gs ? cB : cA)) : 0.0f;
            }
        }
        lsa += (p[0] + p[2]) + (p[4] + p[6]);
        lsb += (p[1] + p[3]) + (p[5] + p[7]);
        {
            union { unsigned short us[4]; unsigned long long u64; } pka, pkb;
            pka.us[0] = f2b(p[0]); pka.us[1] = f2b(p[2]); pka.us[2] = f2b(p[4]); pka.us[3] = f2b(p[6]);
            pkb.us[0] = f2b(p[1]); pkb.us[1] = f2b(p[3]); pkb.us[2] = f2b(p[5]); pkb.us[3] = f2b(p[7]);
            const int ra = gt1 * 32 + l15;
            *reinterpret_cast<unsigned long long*>(
                sP[buf] + ra * 40 + mt1 * 16 + quad * 4) = pka.u64;
            *reinterpret_cast<unsigned long long*>(
                sP[buf] + (ra + 16) * 40 + mt1 * 16 + quad * 4) = pkb.u64;
        }

        // ---- single barrier per tile: sP[buf] visible (no vmem drain)
        asm volatile("s_waitcnt lgkmcnt(0)\n" ::: "memory");
        __builtin_amdgcn_s_barrier();

        // ---- issue next tile's LDS gathers; GEMM2 + prefetchT hide their latency
        if (k + 1 < count) {
            gather(t4n);
            if (k + 2 < count) t4n = times4(cur + 2);
        }

        // ---- GEMM2: A = tf regs (prefetched), B = 4 P-frags (64 g) from sP[buf]
        {
            short8 bP[4];
#pragma unroll
            for (int j = 0; j < 4; ++j)
                bP[j] = *reinterpret_cast<const short8*>(sP[buf] + (j * 16 + l15) * 40 + quad * 8);
            __builtin_amdgcn_s_setprio(1);
#pragma unroll
            for (int mt = 0; mt < 8; ++mt) {
#pragma unroll
                for (int j = 0; j < 4; ++j)
                    accO[mt][j] = __builtin_amdgcn_mfma_f32_16x16x32_bf16(tf[mt], bP[j], accO[mt][j], 0, 0, 0);
            }
            __builtin_amdgcn_s_setprio(0);
        }
        if (k + 1 < count) prefetchT(cur + 1);
    }

    // ---- l reduction: quads via shfl, mt1 halves via LDS
    lsa += __shfl_xor(lsa, 16, 64);
    lsa += __shfl_xor(lsa, 32, 64);
    lsb += __shfl_xor(lsb, 16, 64);
    lsb += __shfl_xor(lsb, 32, 64);
    if (lane < 16) {
        s_lred[mt1][gt1 * 32 + lane] = lsa;
        s_lred[mt1][gt1 * 32 + 16 + lane] = lsb;
    }
    __syncthreads();

    if (w == 0)
        pl[((size_t)s * BB + b) * GG + g0 + lane] = s_lred[0][lane] + s_lred[1][lane];

    ushort_t* po = pO + (((size_t)s * BB + b) * GG) * DD;
#pragma unroll
    for (int mt = 0; mt < 8; ++mt) {
#pragma unroll
        for (int gtt = 0; gtt < 4; ++gtt) {
            union { unsigned short us[4]; unsigned long long u64; } pk;
            pk.us[0] = f2b(accO[mt][gtt][0]); pk.us[1] = f2b(accO[mt][gtt][1]);
            pk.us[2] = f2b(accO[mt][gtt][2]); pk.us[3] = f2b(accO[mt][gtt][3]);
            const int g = g0 + gtt * 16 + l15;
            const int d = w * 128 + mt * 16 + quad * 4;
            *reinterpret_cast<unsigned long long*>(po + (size_t)g * DD + d) = pk.u64;
        }
    }
}

// ---------------- combine: out = (sum_s O_s) / (sum_s l_s) ----------------
template <int NS>
__global__ void combine3(const ushort_t* __restrict__ pO,
                         const float* __restrict__ pl,
                         float* __restrict__ out) {
    const size_t i4 = (size_t)blockIdx.x * 256 + threadIdx.x;
    const size_t base = i4 * 4;                 // 4 d's
    const size_t bg = base >> 9;                // (b*G+g), DD=512
    float lsum = 0.f;
#pragma unroll
    for (int s = 0; s < NS; ++s) lsum += pl[(size_t)s * BB * GG + bg];
    const float inv = 1.0f / lsum;
    float o[4] = {0.f, 0.f, 0.f, 0.f};
#pragma unroll
    for (int s = 0; s < NS; ++s) {
        union { unsigned long long u64; unsigned short us[4]; } pk;
        pk.u64 = *reinterpret_cast<const unsigned long long*>(
            pO + (size_t)s * BB * GG * DD + base);
#pragma unroll
        for (int j = 0; j < 4; ++j) o[j] += b2f(pk.us[j]);
    }
    float4 v;
    v.x = o[0] * inv; v.y = o[1] * inv; v.z = o[2] * inv; v.w = o[3] * inv;
    *reinterpret_cast<float4*>(out + base) = v;
}

// ---------------- round-2 proven fallback (tiny ws) ----------------
__global__ void emb_kernel(const float* __restrict__ times,
                           const float* __restrict__ type_emb,
                           ushort_t* __restrict__ emb) {
    const int row = blockIdx.x;
    const int b = row >> 12;
    const int n = row & (NN - 1);
    const int t = n >> 11;
    const int l = n & (LL - 1);
    const float tm = times[(size_t)(t * BB + b) * LL + l];
    const float pad = (tm != 0.0f) ? 1.0f : 0.0f;
    const int tid = threadIdx.x;
#pragma unroll
    for (int i = 0; i < 2; ++i) {
        int d = i * 256 + tid;
        float theta = tm * inv_pos_f(d >> 1);
        float v = (d & 1) ? cosf(theta) : sinf(theta);
        v = (v + type_emb[t * DD + d]) * pad;
        emb[(size_t)row * DD + d] = f2b(v);
    }
}
__global__ void qgrid_kernel(float* __restrict__ qbuf) {
    const int g = blockIdx.x;
    const int tid = threadIdx.x;
    const float mid = (float)g + 0.5f;
#pragma unroll
    for (int i = 0; i < 4; ++i) {
        int d = i * 128 + tid;
        float theta = mid * inv_pos_f(d >> 1);
        float v = (d & 1) ? cosf(theta) : sinf(theta);
        qbuf[(size_t)g * DD + d] = v;
    }
}
__global__ void attn_kernel(const ushort_t* __restrict__ emb,
                            const float* __restrict__ qbuf,
                            const int* __restrict__ real_len,
                            float* __restrict__ out) {
    __shared__ float s_lds[NN];
    __shared__ float q_s[DD];
    __shared__ float red[8];
    const int blk = blockIdx.x;
    const int b = blk >> 10;
    const int g = blk & (GG - 1);
    const int tid = threadIdx.x;
    const int lane = tid & 63;
    const int wave = tid >> 6;
    q_s[tid]       = qbuf[(size_t)g * DD + tid];
    q_s[tid + 256] = qbuf[(size_t)g * DD + tid + 256];
    __syncthreads();
    float qr[8];
#pragma unroll
    for (int j = 0; j < 8; ++j) qr[j] = q_s[lane * 8 + j];
    const unsigned int* embB =
        reinterpret_cast<const unsigned int*>(emb) + (size_t)b * NN * (DD / 2);
#pragma unroll 2
    for (int it = 0; it < NN / 4; ++it) {
        const int n = it * 4 + wave;
        const uint4 raw = *reinterpret_cast<const uint4*>(embB + (size_t)n * (DD / 2) + lane * 4);
        float sacc = 0.f;
        sacc = fmaf(__uint_as_float(raw.x << 16),         qr[0], sacc);
        sacc = fmaf(__uint_as_float(raw.x & 0xffff0000u), qr[1], sacc);
        sacc = fmaf(__uint_as_float(raw.y << 16),         qr[2], sacc);
        sacc = fmaf(__uint_as_float(raw.y & 0xffff0000u), qr[3], sacc);
        sacc = fmaf(__uint_as_float(raw.z << 16),         qr[4], sacc);
        sacc = fmaf(__uint_as_float(raw.z & 0xffff0000u), qr[5], sacc);
        sacc = fmaf(__uint_as_float(raw.w << 16),         qr[6], sacc);
        sacc = fmaf(__uint_as_float(raw.w & 0xffff0000u), qr[7], sacc);
#pragma unroll
        for (int off = 32; off; off >>= 1) sacc += __shfl_xor(sacc, off, 64);
        if (lane == 0) s_lds[n] = sacc * SCALE;
    }
    __syncthreads();
    const int rl0 = real_len[b];
    const int rl1 = real_len[BB + b];
    float m = -INFINITY;
    float sv[16];
#pragma unroll
    for (int i = 0; i < 16; ++i) {
        const int n = i * 256 + tid;
        float sc = s_lds[n];
        const int l = n & (LL - 1);
        const bool valid = l < ((n < LL) ? rl0 : rl1);
        sc = valid ? sc : -INFINITY;
        sv[i] = sc;
        m = fmaxf(m, sc);
    }
#pragma unroll
    for (int off = 32; off; off >>= 1) m = fmaxf(m, __shfl_xor(m, off, 64));
    if (lane == 0) red[wave] = m;
    __syncthreads();
    m = fmaxf(fmaxf(red[0], red[1]), fmaxf(red[2], red[3]));
    float lsum = 0.f;
#pragma unroll
    for (int i = 0; i < 16; ++i) {
        const int n = i * 256 + tid;
        const float e = expf(sv[i] - m);
        s_lds[n] = e;
        lsum += e;
    }
#pragma unroll
    for (int off = 32; off; off >>= 1) lsum += __shfl_xor(lsum, off, 64);
    if (lane == 0) red[4 + wave] = lsum;
    __syncthreads();
    const float inv_l = 1.0f / (red[4] + red[5] + red[6] + red[7]);
    float acc[8] = {0.f, 0.f, 0.f, 0.f, 0.f, 0.f, 0.f, 0.f};
#pragma unroll 2
    for (int kk = 0; kk < NN / 4; ++kk) {
        const int n = kk * 4 + wave;
        const float p = s_lds[n];
        const uint4 raw = *reinterpret_cast<const uint4*>(embB + (size_t)n * (DD / 2) + lane * 4);
        acc[0] = fmaf(p, __uint_as_float(raw.x << 16),         acc[0]);
        acc[1] = fmaf(p, __uint_as_float(raw.x & 0xffff0000u), acc[1]);
        acc[2] = fmaf(p, __uint_as_float(raw.y << 16),         acc[2]);
        acc[3] = fmaf(p, __uint_as_float(raw.y & 0xffff0000u), acc[3]);
        acc[4] = fmaf(p, __uint_as_float(raw.z << 16),         acc[4]);
        acc[5] = fmaf(p, __uint_as_float(raw.z & 0xffff0000u), acc[5]);
        acc[6] = fmaf(p, __uint_as_float(raw.w << 16),         acc[6]);
        acc[7] = fmaf(p, __uint_as_float(raw.w & 0xffff0000u), acc[7]);
    }
    __syncthreads();
    *reinterpret_cast<float4*>(&s_lds[wave * DD + lane * 8])     = make_float4(acc[0], acc[1], acc[2], acc[3]);
    *reinterpret_cast<float4*>(&s_lds[wave * DD + lane * 8 + 4]) = make_float4(acc[4], acc[5], acc[6], acc[7]);
    __syncthreads();
    {
        const int d0 = tid * 2;
        const float o0 = (s_lds[d0]     + s_lds[DD + d0]     + s_lds[2 * DD + d0]     + s_lds[3 * DD + d0])     * inv_l;
        const float o1 = (s_lds[d0 + 1] + s_lds[DD + d0 + 1] + s_lds[2 * DD + d0 + 1] + s_lds[3 * DD + d0 + 1]) * inv_l;
        *reinterpret_cast<float2*>(out + (size_t)blk * DD + d0) = make_float2(o0, o1);
    }
}

extern "C" void kernel_launch(void* const* d_in, const int* in_sizes, int n_in,
                              void* d_out, int out_size, void* d_ws, size_t ws_size,
                              hipStream_t stream) {
    const float* times    = (const float*)d_in[0];
    const float* type_emb = (const float*)d_in[1];
    const int*   real_len = (const int*)d_in[2];
    float* out = (float*)d_out;

    const size_t embTBytes = (size_t)BB * DD * NN * sizeof(ushort_t);    // 64 MiB
    const size_t tabBytes  = 64 * 1024;                                  // F4 (32KB) + G (8KB) + pad
    const size_t pOslice   = (size_t)BB * GG * DD * sizeof(ushort_t);    // 16 MiB (bf16)
    const size_t plslice   = (size_t)BB * GG * sizeof(float);            // 64 KiB

    ushort_t* embT = (ushort_t*)d_ws;
    float* Ftab = (float*)((char*)d_ws + embTBytes);
    float* Gtab = (float*)((char*)d_ws + embTBytes + 32 * 1024);
    char* pbase = (char*)d_ws + embTBytes + tabBytes;

    auto need = [&](size_t ns) { return embTBytes + tabBytes + ns * (pOslice + plslice); };

    int NS = 0;
    if      (ws_size >= need(4)) NS = 4;
    else if (ws_size >= need(2)) NS = 2;

    if (NS > 0) {
        genT_kernel<<<BB * 64, 256, 0, stream>>>(times, type_emb, embT);
        ftab4_kernel<<<64, 256, 0, stream>>>(Ftab);
        gq_kernel<<<GG, 256, 0, stream>>>(type_emb, Gtab);
        ushort_t* pO = (ushort_t*)pbase;
        float* pl = (float*)(pbase + (size_t)NS * pOslice);
        if (NS == 4) {
            attn7<4><<<4 * 256, 256, 0, stream>>>(times, embT, Ftab, Gtab, real_len, pO, pl);
            combine3<4><<<(BB * GG * DD) / (256 * 4), 256, 0, stream>>>(pO, pl, out);
        } else {
            attn7<2><<<2 * 256, 256, 0, stream>>>(times, embT, Ftab, Gtab, real_len, pO, pl);
            combine3<2><<<(BB * GG * DD) / (256 * 4), 256, 0, stream>>>(pO, pl, out);
        }
    } else {
        // fallback: 66 MiB footprint (proven in round 2)
        ushort_t* emb = (ushort_t*)d_ws;
        float* qbuf = (float*)((char*)d_ws + embTBytes);
        emb_kernel<<<BB * NN, 256, 0, stream>>>(times, type_emb, emb);
        qgrid_kernel<<<GG, 128, 0, stream>>>(qbuf);
        attn_kernel<<<BB * GG, 256, 0, stream>>>(emb, qbuf, real_len, out);
    }
}